// Round 15
// baseline (138.327 us; speedup 1.0000x reference)
//
#include <hip/hip_runtime.h>
#include <hip/hip_bf16.h>
#include <math.h>

namespace {

constexpr int Bc = 2;
constexpr int Sc = 2048;
constexpr int Ec = 1024;
constexpr int Hc = 8;
constexpr int Dc = 128;
constexpr int Mc = Bc * Sc; // 4096

typedef unsigned short u16;
typedef unsigned int   u32;
typedef u16    u16x8  __attribute__((ext_vector_type(8)));
typedef u16    u16x4  __attribute__((ext_vector_type(4)));
typedef __bf16 bf16x8 __attribute__((ext_vector_type(8)));
typedef float  f32x4  __attribute__((ext_vector_type(4)));

static __device__ inline bf16x8 asbf(u16x8 v) { return __builtin_bit_cast(bf16x8, v); }

static __device__ inline f32x4 mfma16(u16x8 a, u16x8 b, f32x4 c) {
    return __builtin_amdgcn_mfma_f32_16x16x32_bf16(asbf(a), asbf(b), c, 0, 0, 0);
}

static __device__ inline u16 f2bf(float f) {
    unsigned u = __builtin_bit_cast(unsigned, f);
    return (u16)((u + 0x7fffu + ((u >> 16) & 1u)) >> 16);
}
static __device__ inline float bf2f(u16 h) {
    unsigned u = ((unsigned)h) << 16;
    return __builtin_bit_cast(float, u);
}

// Async global->LDS DMA, 16B per lane.  LDS dest wave-uniform; HW writes
// lane l at dest + l*16B.
static __device__ inline void gload16(const u16* g, u16* l) {
    __builtin_amdgcn_global_load_lds(
        (__attribute__((address_space(1))) void*)const_cast<u16*>(g),
        (__attribute__((address_space(3))) void*)l,
        16, 0, 0);
}

// BK=32 LDS layout (rows of 32 elems = 64B), 2-way-bank-free swizzle (used
// by mgemmO only): blob(R, c') holds source chunk c = c' ^ g(R), g = (R>>1)&3.
#define AIDX(R_, hi_) (((R_) * 32) + (((hi_) ^ (((R_) >> 1) & 3)) << 3))

// ---------------------------------------------------------------------------
// Fused prep: convX | head-weight transpose | square-weight transpose | trig.
// Grid 7680 x 256; block-uniform range dispatch.
// ---------------------------------------------------------------------------
__global__ __launch_bounds__(256) void prep(const float* __restrict__ X,
                                            const float* __restrict__ W_Q,
                                            const float* __restrict__ W_K,
                                            const float* __restrict__ W_V,
                                            const float* __restrict__ W_G,
                                            const float* __restrict__ W_O,
                                            u16* __restrict__ Xb,
                                            u16* __restrict__ Wh,
                                            u16* __restrict__ Wsq,
                                            float2* __restrict__ tabQ,
                                            float2* __restrict__ tabK)
{
    const int bid = blockIdx.x, tid = threadIdx.x;
    __shared__ float tile[32][33];

    if (bid < 2048) {               // ---- X f32 -> bf16 (NX/8 = 524288) ----
        const int i = bid * 256 + tid;
        float4 a = *(const float4*)(X + (size_t)i * 8);
        float4 b = *(const float4*)(X + (size_t)i * 8 + 4);
        u16x8 o;
        o[0] = f2bf(a.x); o[1] = f2bf(a.y); o[2] = f2bf(a.z); o[3] = f2bf(a.w);
        o[4] = f2bf(b.x); o[5] = f2bf(b.y); o[6] = f2bf(b.z); o[7] = f2bf(b.w);
        *(u16x8*)(Xb + (size_t)i * 8) = o;
    } else if (bid < 5120) {        // ---- head weights: [1024][128] -> T ----
        const int idx = bid - 2048;           // 0..3071  (z 0..23, 128 tiles)
        const int z = idx >> 7, rem = idx & 127;
        const int r0 = (rem >> 2) * 32, c0 = (rem & 3) * 32;
        const float* ip = (z < 8 ? W_Q : z < 16 ? W_K : W_V) + (size_t)(z & 7) * Ec * Dc;
        u16* op = Wh + (size_t)z * Dc * Ec;
        const int ty = tid >> 5, tx = tid & 31;
#pragma unroll
        for (int i = ty; i < 32; i += 8) tile[i][tx] = ip[(size_t)(r0 + i) * Dc + c0 + tx];
        __syncthreads();
#pragma unroll
        for (int i = ty; i < 32; i += 8) op[(size_t)(c0 + i) * Ec + r0 + tx] = f2bf(tile[tx][i]);
    } else if (bid < 7168) {        // ---- square weights: [1024][1024] -> T --
        const int idx = bid - 5120;           // 0..2047 (z 0..1, 1024 tiles)
        const int z = idx >> 10, rem = idx & 1023;
        const int r0 = (rem >> 5) * 32, c0 = (rem & 31) * 32;
        const float* ip = z == 0 ? W_G : W_O;
        u16* op = Wsq + (size_t)z * Ec * Ec;
        const int ty = tid >> 5, tx = tid & 31;
#pragma unroll
        for (int i = ty; i < 32; i += 8) tile[i][tx] = ip[(size_t)(r0 + i) * Ec + c0 + tx];
        __syncthreads();
#pragma unroll
        for (int i = ty; i < 32; i += 8) op[(size_t)(c0 + i) * Ec + r0 + tx] = f2bf(tile[tx][i]);
    } else {                        // ---- xPos trig tables (2048*64) ----
        const int i = (bid - 7168) * 256 + tid;
        const int s = i >> 6, ip = i & 63;
        float sv = (2.f * (float)ip + 51.2f) * (1.f / 179.2f);
        float sc = exp2f(((float)s * (1.f / 512.f)) * log2f(sv));
        float freq = exp2f(-(float)ip * (13.287712379549449f / 64.f));
        float ang = (float)s * freq;
        float sn, cs;
        sincosf(ang, &sn, &cs);
        tabQ[i] = make_float2(cs * sc, sn * sc);
        tabK[i] = make_float2(cs / sc, sn / sc);
    }
}

// ---------------------------------------------------------------------------
// 256x256 projection GEMM, counted-vmcnt schedule (r11 form — PROVEN 49.4us,
// VGPR 96, 0 bank conflicts).  r12 lesson: launch_bounds(512,4) capped VGPRs
// -> acc spilled to scratch (543 MB writes, 4x slowdown).  Keep (512, 2).
// ---------------------------------------------------------------------------
__global__ __launch_bounds__(512, 2) void mgemm4(const u16* __restrict__ A,
                                                 const u16* __restrict__ Ball,
                                                 u16* __restrict__ Qo,
                                                 u16* __restrict__ Ko,
                                                 u16* __restrict__ Vo,
                                                 u16* __restrict__ Go,
                                                 const float2* __restrict__ tabQ,
                                                 const float2* __restrict__ tabK)
{
    const int t = threadIdx.x, lane = t & 63, wid = t >> 6;
    const int wm = wid >> 2, wn = wid & 3;
    const int rl = lane & 15, hi = lane >> 4;
    const int r0 = blockIdx.x * 256;
    const int wsel = blockIdx.y >> 2;
    const int n0 = (blockIdx.y & 3) * 256;
    const u16* Bt = Ball + (size_t)wsel * Ec * Ec;

    __shared__ u16 lds[2][2][256 * 64]; // [buf][A/B][row*64 + col], 128 KiB

    f32x4 acc[8][4] = {};

    const int srow = lane >> 3;                       // 0..7 within 8-row issue
    const int scol = (((lane & 7) ^ srow) << 3);      // elems (pre-swizzled)
    const u16* Asrc = A  + (size_t)(r0 + wid * 32 + srow) * Ec + scol;
    const u16* Bsrc = Bt + (size_t)(n0 + wid * 32 + srow) * Ec + scol;

#define STAGE256(tile, buf)                                                     \
    do {                                                                        \
        const int _k0 = (tile) * 64;                                            \
        _Pragma("unroll")                                                       \
        for (int i = 0; i < 4; ++i) {                                           \
            gload16(Asrc + (size_t)(i * 8) * Ec + _k0,                          \
                    &lds[buf][0][(wid * 32 + i * 8) * 64]);                     \
            gload16(Bsrc + (size_t)(i * 8) * Ec + _k0,                          \
                    &lds[buf][1][(wid * 32 + i * 8) * 64]);                     \
        }                                                                       \
    } while (0)

    STAGE256(0, 0);
    for (int tt = 0; tt < 16; ++tt) {
        const int buf = tt & 1;
        if (tt + 1 < 16) {
            STAGE256(tt + 1, buf ^ 1);
            asm volatile("s_waitcnt vmcnt(8)" ::: "memory"); // my tile-tt loads
        } else {
            asm volatile("s_waitcnt vmcnt(0)" ::: "memory");
        }
        __builtin_amdgcn_s_barrier();   // ALL waves' tile-tt DMAs landed

        u16x8 breg[4][2];
#pragma unroll
        for (int cf = 0; cf < 4; ++cf)
#pragma unroll
            for (int ks = 0; ks < 2; ++ks) {
                const int row = wn * 64 + cf * 16 + rl;
                breg[cf][ks] = *(const u16x8*)
                    &lds[buf][1][row * 64 + ((ks * 32 + hi * 8) ^ ((rl & 7) << 3))];
            }
#pragma unroll
        for (int q = 0; q < 4; ++q) {
            u16x8 areg[2][2];
#pragma unroll
            for (int rfi = 0; rfi < 2; ++rfi)
#pragma unroll
                for (int ks = 0; ks < 2; ++ks) {
                    const int row = wm * 128 + (q * 2 + rfi) * 16 + rl;
                    areg[rfi][ks] = *(const u16x8*)
                        &lds[buf][0][row * 64 + ((ks * 32 + hi * 8) ^ ((rl & 7) << 3))];
                }
            __builtin_amdgcn_s_setprio(1);
#pragma unroll
            for (int rfi = 0; rfi < 2; ++rfi)
#pragma unroll
                for (int cf = 0; cf < 4; ++cf)
#pragma unroll
                    for (int ks = 0; ks < 2; ++ks)
                        acc[q * 2 + rfi][cf] =
                            mfma16(breg[cf][ks], areg[rfi][ks], acc[q * 2 + rfi][cf]);
            __builtin_amdgcn_s_setprio(0);
        }
        __builtin_amdgcn_s_barrier();   // reads of buf done before overwrite
    }
#undef STAGE256

    u16* Cout = wsel == 0 ? Qo : wsel == 1 ? Ko : wsel == 2 ? Vo : Go;
    const float2* tab = wsel == 0 ? tabQ : tabK;

#pragma unroll
    for (int rf = 0; rf < 8; ++rf) {
        const int row = r0 + wm * 128 + rf * 16 + rl;
#pragma unroll
        for (int cf = 0; cf < 4; ++cf) {
            const int col0 = n0 + wn * 64 + cf * 16 + hi * 4;
            f32x4 v = acc[rf][cf];
            if (wsel <= 1) { // xPos rotate: pairs (0,1),(2,3) lane-local
                const size_t tb = (size_t)(row & 2047) * 64 + ((col0 >> 1) & 63);
                const float2 c0 = tab[tb];
                const float2 c1 = tab[tb + 1];
                float e0 = v[0], o0 = v[1], e1 = v[2], o1 = v[3];
                v[0] = e0 * c0.x - o0 * c0.y;
                v[1] = o0 * c0.x + e0 * c0.y;
                v[2] = e1 * c1.x - o1 * c1.y;
                v[3] = o1 * c1.x + e1 * c1.y;
            } else if (wsel == 3) { // silu
#pragma unroll
                for (int r = 0; r < 4; ++r) v[r] = v[r] / (1.f + expf(-v[r]));
            }
            u16x4 pk;
#pragma unroll
            for (int r = 0; r < 4; ++r) pk[r] = f2bf(v[r]);
            *(u16x4*)(Cout + (size_t)row * Ec + col0) = pk;
        }
    }
}

// ---------------------------------------------------------------------------
// Final GEMM: out(f32) = Z x WoT^T.  128x64 tile, BK=32, 4 waves, grid
// (32,16)=512 blocks -> 2 blocks/CU.  3 gloads/wave/tile, vmcnt(3),
// 8 MFMA/tile, BK=32 swizzle (AIDX).
// ---------------------------------------------------------------------------
__global__ __launch_bounds__(256) void mgemmO(const u16* __restrict__ A,
                                              const u16* __restrict__ Bt,
                                              float* __restrict__ Cout)
{
    const int t = threadIdx.x, lane = t & 63, w = t >> 6;
    const int rl = lane & 15, hi = lane >> 4;
    const int r0 = blockIdx.x * 128;
    const int n0 = blockIdx.y * 64;

    __shared__ u16 Ab[2][128 * 32]; // 16 KiB
    __shared__ u16 Bb[2][64 * 32];  //  8 KiB

    f32x4 acc[2][4] = {};

    const int srow = lane >> 2;
    const int schunk = (lane & 3) ^ ((lane >> 3) & 3);
    const u16* Asrc = A  + (size_t)(r0 + w * 32 + srow) * Ec + schunk * 8;
    const u16* Bsrc = Bt + (size_t)(n0 + w * 16 + srow) * Ec + schunk * 8;

#define STAGEO(tile_, buf_)                                                   \
    do {                                                                      \
        const int _k0 = (tile_) * 32;                                         \
        gload16(Asrc + _k0,                   &Ab[buf_][(w * 32) * 32]);      \
        gload16(Asrc + (size_t)16 * Ec + _k0, &Ab[buf_][(w * 32 + 16) * 32]); \
        gload16(Bsrc + _k0,                   &Bb[buf_][(w * 16) * 32]);      \
    } while (0)

    STAGEO(0, 0);
    for (int tt = 0; tt < 32; ++tt) {
        const int buf = tt & 1;
        if (tt + 1 < 32) {
            STAGEO(tt + 1, buf ^ 1);
            asm volatile("s_waitcnt vmcnt(3)" ::: "memory");
        } else {
            asm volatile("s_waitcnt vmcnt(0)" ::: "memory");
        }
        __builtin_amdgcn_s_barrier();

        u16x8 breg[4], areg[2];
#pragma unroll
        for (int cf = 0; cf < 4; ++cf)
            breg[cf] = *(const u16x8*)&Bb[buf][AIDX(cf * 16 + rl, hi)];
#pragma unroll
        for (int rfi = 0; rfi < 2; ++rfi)
            areg[rfi] = *(const u16x8*)&Ab[buf][AIDX(w * 32 + rfi * 16 + rl, hi)];
        __builtin_amdgcn_s_setprio(1);
#pragma unroll
        for (int rfi = 0; rfi < 2; ++rfi)
#pragma unroll
            for (int cf = 0; cf < 4; ++cf)
                acc[rfi][cf] = mfma16(breg[cf], areg[rfi], acc[rfi][cf]);
        __builtin_amdgcn_s_setprio(0);
        __builtin_amdgcn_s_barrier();
    }
#undef STAGEO

#pragma unroll
    for (int rfi = 0; rfi < 2; ++rfi) {
        const int row = r0 + w * 32 + rfi * 16 + rl;
#pragma unroll
        for (int cf = 0; cf < 4; ++cf) {
            const int col0 = n0 + cf * 16 + hi * 4;
            *(f32x4*)(Cout + (size_t)row * Ec + col0) = acc[rfi][cf];
        }
    }
}

// ---------------------------------------------------------------------------
// Retention + fused GroupNorm*gate, QBLK=128 (r15): block = 128 Q-rows x one
// (b,h), 512 threads = 8 waves in 2 groups.  Same staged 64-wide K/V chunk
// feeds 2x the Q-rows: staging traffic and chunk count HALVE, MFMA per
// barrier-triple DOUBLES (r14 showed occupancy isn't the lever; per-chunk
// staging+barrier cost is).
// Grid 256, id: slot = id&15 (xcd = slot&7 hosts heads {h,7-h}, L2-resident
// K/V), rb = id>>4 (0..15).
// QK: group g = wid>>2 owns Q-rows [g*64,+64) (qf[4][4] regs, staged in 2
// passes through Ks); wave w4 = wid&3 owns m-strip.  SV: wave wid owns
// n-strip [wid*16,+16) of 128.  Single-buffered K/V/Ss, 3 barriers/chunk.
// ---------------------------------------------------------------------------
__global__ __launch_bounds__(512) void ret_gn(const u16* __restrict__ Q,
                                              const u16* __restrict__ K,
                                              const u16* __restrict__ V,
                                              const u16* __restrict__ G,
                                              const float* __restrict__ gw,
                                              const float* __restrict__ gbias,
                                              u16* __restrict__ Z)
{
    const int t = threadIdx.x, lane = t & 63, wid = t >> 6;
    const int w4 = wid & 3, g = wid >> 2;
    const int rl = lane & 15, hi = lane >> 4;
    const int id = blockIdx.x;
    const int slot = id & 15;
    const int rb = id >> 4;            // 0..15, 128-row block
    const int b = slot >> 3;
    const int h = b == 0 ? (slot & 7) : 7 - (slot & 7);

    __shared__ u16 Ks[64][136];  // 17.4 KB (also Q staging, 2 passes)
    __shared__ u16 Vt[128][68];  // 17.4 KB, V transposed: Vt[d][m]
    __shared__ u16 Ss[128][72];  // 18.4 KB, S[n][m], n = 0..127

    const float lga = -3.4657359027997265f; // log(1/32)
    const float lgb = -6.2383246250395075f; // log(1/512)
    const float gamma = 1.f - expf(lga + (float)h * (lgb - lga) * (1.f / 7.f));
    const float lg2 = log2f(gamma);

    int c_lo = 0;
    {
        float cut = 9.2103404f / (-logf(gamma)); // weight >= ~1e-4
        int mmin = rb * 128 - (int)cut;
        if (mmin > 0) c_lo = mmin >> 6;
    }
    const int c_hi = 2 * rb + 1;

    // per-lane staging geometry (512 threads)
    const int ki = t >> 3,        kq = (t & 7) * 16;  // K: row, 16-elem col
    const int vm2 = (t & 31) * 2, vd = (t >> 5) * 8;  // V: 2 rows, 8-d segment
    const u16* Kg0 = K + (size_t)(b * Sc) * Ec + h * Dc;
    const u16* Vg0 = V + (size_t)(b * Sc) * Ec + h * Dc;

    // ---- issue first K/V chunk loads (independent of LDS) ----
    u16x8 kreg[2], vreg[2];
    {
        const u16* Kg = Kg0 + (size_t)(c_lo * 64 + ki) * Ec + kq;
        kreg[0] = *(const u16x8*)(Kg);
        kreg[1] = *(const u16x8*)(Kg + 8);
        const u16* Vg = Vg0 + (size_t)(c_lo * 64 + vm2) * Ec + vd;
        vreg[0] = *(const u16x8*)(Vg);
        vreg[1] = *(const u16x8*)(Vg + Ec);
    }

    // ---- stage Q in 2 passes through Ks; group g reads pass g ----
    u16x8 qf[4][4];
#pragma unroll
    for (int pass = 0; pass < 2; ++pass) {
        const u16* Qg = Q + (size_t)(b * Sc + rb * 128 + pass * 64 + ki) * Ec + h * Dc + kq;
        u16x8 q0 = *(const u16x8*)(Qg);
        u16x8 q1 = *(const u16x8*)(Qg + 8);
        __syncthreads();   // pass1: prior pass's qf reads complete
        *(u16x8*)&Ks[ki][kq]     = q0;
        *(u16x8*)&Ks[ki][kq + 8] = q1;
        __syncthreads();
        if (g == pass) {
#pragma unroll
            for (int nt = 0; nt < 4; ++nt)
#pragma unroll
                for (int ks = 0; ks < 4; ++ks)
                    qf[nt][ks] = *(const u16x8*)&Ks[nt * 16 + rl][ks * 32 + hi * 8];
        }
    }
    __syncthreads(); // all qf reads done before chunk loop overwrites Ks

    // decay: wgt(n,m) = nf[nt] * mf[reg];  n = rb*128 + g*64 + nt*16 + rl
    float mf[4];
#pragma unroll
    for (int reg = 0; reg < 4; ++reg)
        mf[reg] = exp2f(-lg2 * (float)(w4 * 16 + hi * 4 + reg));
    float nf[4];
#pragma unroll
    for (int nt = 0; nt < 4; ++nt)
        nf[nt] = exp2f(lg2 * (float)(rb * 128 + g * 64 + nt * 16 + rl - c_lo * 64));
    const float ginv64 = exp2f(-lg2 * 64.f);

    f32x4 yacc[8] = {};

    for (int c = c_lo; c <= c_hi; ++c) {
        // regs -> LDS (single buffer; prior reads fenced by end-of-chunk bar)
        *(u16x8*)&Ks[ki][kq]     = kreg[0];
        *(u16x8*)&Ks[ki][kq + 8] = kreg[1];
#pragma unroll
        for (int j = 0; j < 8; ++j)
            *(u32*)&Vt[vd + j][vm2] = (u32)vreg[0][j] | ((u32)vreg[1][j] << 16);
        __syncthreads();
        if (c < c_hi) { // prefetch next chunk into REGISTERS under compute
            const u16* Kg = Kg0 + (size_t)((c + 1) * 64 + ki) * Ec + kq;
            kreg[0] = *(const u16x8*)(Kg);
            kreg[1] = *(const u16x8*)(Kg + 8);
            const u16* Vg = Vg0 + (size_t)((c + 1) * 64 + vm2) * Ec + vd;
            vreg[0] = *(const u16x8*)(Vg);
            vreg[1] = *(const u16x8*)(Vg + Ec);
        }

        // QK^T: group g computes S rows [g*64, g*64+64); wave w4 owns m-strip
        __builtin_amdgcn_s_setprio(1);
        u16x8 kf[4];
#pragma unroll
        for (int ks = 0; ks < 4; ++ks)
            kf[ks] = *(const u16x8*)&Ks[w4 * 16 + rl][ks * 32 + hi * 8];
        const int cg = 2 * rb + g;   // diagonal chunk for this group
#pragma unroll
        for (int nt = 0; nt < 4; ++nt) {
            f32x4 s = {};
#pragma unroll
            for (int ks = 0; ks < 4; ++ks)
                s = mfma16(kf[ks], qf[nt][ks], s);
            // lane holds S[nloc = g*64+nt*16+rl][m = w4*16+hi*4+reg]
            u16x4 pk;
#pragma unroll
            for (int reg = 0; reg < 4; ++reg) {
                float wgt = nf[nt] * mf[reg];
                if (c > cg || (c == cg && (w4 * 16 + hi * 4 + reg) > (nt * 16 + rl)))
                    wgt = 0.f;
                pk[reg] = f2bf(s[reg] * wgt);
            }
            *(u16x4*)&Ss[g * 64 + nt * 16 + rl][w4 * 16 + hi * 4] = pk;
        }
        __builtin_amdgcn_s_setprio(0);
        __syncthreads();

        // Y += S V: wave wid owns n-strip [wid*16, +16) of 128
        u16x8 sf0 = *(const u16x8*)&Ss[wid * 16 + rl][hi * 8];
        u16x8 sf1 = *(const u16x8*)&Ss[wid * 16 + rl][32 + hi * 8];
        __builtin_amdgcn_s_setprio(1);
#pragma unroll
        for (int ct = 0; ct < 8; ++ct) {
            u16x8 vf0 = *(const u16x8*)&Vt[ct * 16 + rl][hi * 8];
            u16x8 vf1 = *(const u16x8*)&Vt[ct * 16 + rl][32 + hi * 8];
            yacc[ct] = mfma16(vf0, sf0, yacc[ct]);
            yacc[ct] = mfma16(vf1, sf1, yacc[ct]);
        }
        __builtin_amdgcn_s_setprio(0);
        __syncthreads();   // single buffer: all reads done before next write
#pragma unroll
        for (int nt = 0; nt < 4; ++nt) nf[nt] *= ginv64;
    }

    // ---- fused GroupNorm * gate epilogue (one row per thread) ----
    const int nloc = wid * 16 + rl;
    const size_t row = (size_t)(b * Sc + rb * 128 + nloc);
    float s = 0.f, sq = 0.f;
#pragma unroll
    for (int ct = 0; ct < 8; ++ct)
#pragma unroll
        for (int reg = 0; reg < 4; ++reg) {
            float v = yacc[ct][reg];
            s += v; sq += v * v;
        }
    s  += __shfl_xor(s, 16);  sq += __shfl_xor(sq, 16);
    s  += __shfl_xor(s, 32);  sq += __shfl_xor(sq, 32);
    const float mu  = s * (1.f / 128.f);
    const float var = sq * (1.f / 128.f) - mu * mu;
    const float inv = rsqrtf(var + 1e-5f);
#pragma unroll
    for (int ct = 0; ct < 8; ++ct) {
        const int col0 = h * Dc + ct * 16 + hi * 4;
        const f32x4 w4v = *(const f32x4*)(gw + col0);
        const f32x4 b4 = *(const f32x4*)(gbias + col0);
        const u16x4 g4 = *(const u16x4*)(G + row * Ec + col0);
        u16x4 z4;
#pragma unroll
        for (int reg = 0; reg < 4; ++reg)
            z4[reg] = f2bf(((yacc[ct][reg] - mu) * inv * w4v[reg] + b4[reg]) * bf2f(g4[reg]));
        *(u16x4*)(Z + row * Ec + col0) = z4;
    }
}

} // anonymous namespace

extern "C" void kernel_launch(void* const* d_in, const int* in_sizes, int n_in,
                              void* d_out, int out_size, void* d_ws, size_t ws_size,
                              hipStream_t stream)
{
    const float* X    = (const float*)d_in[0];
    const float* W_Q  = (const float*)d_in[1];
    const float* W_K  = (const float*)d_in[2];
    const float* W_V  = (const float*)d_in[3];
    const float* W_G  = (const float*)d_in[4];
    const float* W_O  = (const float*)d_in[5];
    const float* gw   = (const float*)d_in[6];
    const float* gb   = (const float*)d_in[7];

    char* ws = (char*)d_ws;
    const size_t NX = (size_t)Mc * Ec;          // 4 Mi elements
    u16*    Xb   = (u16*)ws;                ws += NX * 2;              // 8 MB
    u16*    WqT  = (u16*)ws;                ws += (size_t)Ec * Ec * 2; // 2 MB (x4, contiguous)
    u16*    WkT  = (u16*)ws;                ws += (size_t)Ec * Ec * 2;
    u16*    WvT  = (u16*)ws;                ws += (size_t)Ec * Ec * 2;
    u16*    WgT  = (u16*)ws;                ws += (size_t)Ec * Ec * 2;
    u16*    WoT  = (u16*)ws;                ws += (size_t)Ec * Ec * 2;
    float2* tabQ = (float2*)ws;             ws += (size_t)Sc * 64 * sizeof(float2); // 1 MB
    float2* tabK = (float2*)ws;             ws += (size_t)Sc * 64 * sizeof(float2);
    u16*    Qb   = (u16*)ws;                ws += NX * 2;              // 8 MB
    u16*    Kb   = (u16*)ws;                ws += NX * 2;
    u16*    Vb   = (u16*)ws;                ws += NX * 2;
    u16*    Gb   = (u16*)ws;                ws += NX * 2;
    u16*    Zb   = (u16*)ws;                ws += NX * 2;
    (void)WkT; (void)WvT;

    prep<<<dim3(7680), dim3(256), 0, stream>>>(X, W_Q, W_K, W_V, W_G, W_O,
                                               Xb, WqT, WgT, tabQ, tabK);

    mgemm4<<<dim3(Mc / 256, 16), dim3(512), 0, stream>>>(Xb, WqT, Qb, Kb, Vb, Gb, tabQ, tabK);

    ret_gn<<<dim3(256), dim3(512), 0, stream>>>(Qb, Kb, Vb, Gb, gw, gb, Zb);

    mgemmO<<<dim3(Mc / 128, Ec / 64), dim3(256), 0, stream>>>(Zb, WoT, (float*)d_out);
}

// Round 16
// 125.561 us; speedup vs baseline: 1.1017x; 1.1017x over previous
//
#include <hip/hip_runtime.h>
#include <hip/hip_bf16.h>
#include <math.h>

namespace {

constexpr int Bc = 2;
constexpr int Sc = 2048;
constexpr int Ec = 1024;
constexpr int Hc = 8;
constexpr int Dc = 128;
constexpr int Mc = Bc * Sc; // 4096

typedef unsigned short u16;
typedef u16    u16x8  __attribute__((ext_vector_type(8)));
typedef u16    u16x4  __attribute__((ext_vector_type(4)));
typedef __bf16 bf16x8 __attribute__((ext_vector_type(8)));
typedef float  f32x4  __attribute__((ext_vector_type(4)));

static __device__ inline bf16x8 asbf(u16x8 v) { return __builtin_bit_cast(bf16x8, v); }

static __device__ inline f32x4 mfma16(u16x8 a, u16x8 b, f32x4 c) {
    return __builtin_amdgcn_mfma_f32_16x16x32_bf16(asbf(a), asbf(b), c, 0, 0, 0);
}

static __device__ inline u16 f2bf(float f) {
    unsigned u = __builtin_bit_cast(unsigned, f);
    return (u16)((u + 0x7fffu + ((u >> 16) & 1u)) >> 16);
}
static __device__ inline float bf2f(u16 h) {
    unsigned u = ((unsigned)h) << 16;
    return __builtin_bit_cast(float, u);
}

// Async global->LDS DMA, 16B per lane.  LDS dest wave-uniform; HW writes
// lane l at dest + l*16B.
static __device__ inline void gload16(const u16* g, u16* l) {
    __builtin_amdgcn_global_load_lds(
        (__attribute__((address_space(1))) void*)const_cast<u16*>(g),
        (__attribute__((address_space(3))) void*)l,
        16, 0, 0);
}

// BK=32 LDS layout (rows of 32 elems = 64B), 2-way-bank-free swizzle (used
// by mgemmO only): blob(R, c') holds source chunk c = c' ^ g(R), g = (R>>1)&3.
#define AIDX(R_, hi_) (((R_) * 32) + (((hi_) ^ (((R_) >> 1) & 3)) << 3))

// ---------------------------------------------------------------------------
// Fused prep: convX | head-weight transpose | square-weight transpose | trig.
// Grid 7680 x 256; block-uniform range dispatch.
// ---------------------------------------------------------------------------
__global__ __launch_bounds__(256) void prep(const float* __restrict__ X,
                                            const float* __restrict__ W_Q,
                                            const float* __restrict__ W_K,
                                            const float* __restrict__ W_V,
                                            const float* __restrict__ W_G,
                                            const float* __restrict__ W_O,
                                            u16* __restrict__ Xb,
                                            u16* __restrict__ Wh,
                                            u16* __restrict__ Wsq,
                                            float2* __restrict__ tabQ,
                                            float2* __restrict__ tabK)
{
    const int bid = blockIdx.x, tid = threadIdx.x;
    __shared__ float tile[32][33];

    if (bid < 2048) {               // ---- X f32 -> bf16 (NX/8 = 524288) ----
        const int i = bid * 256 + tid;
        float4 a = *(const float4*)(X + (size_t)i * 8);
        float4 b = *(const float4*)(X + (size_t)i * 8 + 4);
        u16x8 o;
        o[0] = f2bf(a.x); o[1] = f2bf(a.y); o[2] = f2bf(a.z); o[3] = f2bf(a.w);
        o[4] = f2bf(b.x); o[5] = f2bf(b.y); o[6] = f2bf(b.z); o[7] = f2bf(b.w);
        *(u16x8*)(Xb + (size_t)i * 8) = o;
    } else if (bid < 5120) {        // ---- head weights: [1024][128] -> T ----
        const int idx = bid - 2048;           // 0..3071  (z 0..23, 128 tiles)
        const int z = idx >> 7, rem = idx & 127;
        const int r0 = (rem >> 2) * 32, c0 = (rem & 3) * 32;
        const float* ip = (z < 8 ? W_Q : z < 16 ? W_K : W_V) + (size_t)(z & 7) * Ec * Dc;
        u16* op = Wh + (size_t)z * Dc * Ec;
        const int ty = tid >> 5, tx = tid & 31;
#pragma unroll
        for (int i = ty; i < 32; i += 8) tile[i][tx] = ip[(size_t)(r0 + i) * Dc + c0 + tx];
        __syncthreads();
#pragma unroll
        for (int i = ty; i < 32; i += 8) op[(size_t)(c0 + i) * Ec + r0 + tx] = f2bf(tile[tx][i]);
    } else if (bid < 7168) {        // ---- square weights: [1024][1024] -> T --
        const int idx = bid - 5120;           // 0..2047 (z 0..1, 1024 tiles)
        const int z = idx >> 10, rem = idx & 1023;
        const int r0 = (rem >> 5) * 32, c0 = (rem & 31) * 32;
        const float* ip = z == 0 ? W_G : W_O;
        u16* op = Wsq + (size_t)z * Ec * Ec;
        const int ty = tid >> 5, tx = tid & 31;
#pragma unroll
        for (int i = ty; i < 32; i += 8) tile[i][tx] = ip[(size_t)(r0 + i) * Ec + c0 + tx];
        __syncthreads();
#pragma unroll
        for (int i = ty; i < 32; i += 8) op[(size_t)(c0 + i) * Ec + r0 + tx] = f2bf(tile[tx][i]);
    } else {                        // ---- xPos trig tables (2048*64) ----
        const int i = (bid - 7168) * 256 + tid;
        const int s = i >> 6, ip = i & 63;
        float sv = (2.f * (float)ip + 51.2f) * (1.f / 179.2f);
        float sc = exp2f(((float)s * (1.f / 512.f)) * log2f(sv));
        float freq = exp2f(-(float)ip * (13.287712379549449f / 64.f));
        float ang = (float)s * freq;
        float sn, cs;
        sincosf(ang, &sn, &cs);
        tabQ[i] = make_float2(cs * sc, sn * sc);
        tabK[i] = make_float2(cs / sc, sn / sc);
    }
}

// ---------------------------------------------------------------------------
// 256x256 projection GEMM, counted-vmcnt schedule (r11 form — PROVEN 49.4us,
// VGPR 96, 0 bank conflicts).  r12 lesson: launch_bounds(512,4) capped VGPRs
// -> acc spilled to scratch (543 MB writes, 4x slowdown).  Keep (512, 2).
// 512 threads = 8 waves (2 x 4); per-wave output 128x64; BK=64.
// LDS: 2 dbuf x (A 256x64 + B 256x64) bf16; swizzle colb ^= ((row&7)<<4)
// via pre-swizzled global SOURCE + XOR'd ds_read (both-sides, G4/#21).
// Per K-tile: STAGE(t+1), vmcnt(8), s_barrier (certifies ALL waves' tile-t
// DMAs — vmcnt is per-wave), compute, s_barrier (protects buf).
// blockIdx.y: wsel = y>>2 (Q/K/V/G), n0 = (y&3)*256.
// ---------------------------------------------------------------------------
__global__ __launch_bounds__(512, 2) void mgemm4(const u16* __restrict__ A,
                                                 const u16* __restrict__ Ball,
                                                 u16* __restrict__ Qo,
                                                 u16* __restrict__ Ko,
                                                 u16* __restrict__ Vo,
                                                 u16* __restrict__ Go,
                                                 const float2* __restrict__ tabQ,
                                                 const float2* __restrict__ tabK)
{
    const int t = threadIdx.x, lane = t & 63, wid = t >> 6;
    const int wm = wid >> 2, wn = wid & 3;
    const int rl = lane & 15, hi = lane >> 4;
    const int r0 = blockIdx.x * 256;
    const int wsel = blockIdx.y >> 2;
    const int n0 = (blockIdx.y & 3) * 256;
    const u16* Bt = Ball + (size_t)wsel * Ec * Ec;

    __shared__ u16 lds[2][2][256 * 64]; // [buf][A/B][row*64 + col], 128 KiB

    f32x4 acc[8][4] = {};

    const int srow = lane >> 3;                       // 0..7 within 8-row issue
    const int scol = (((lane & 7) ^ srow) << 3);      // elems (pre-swizzled)
    const u16* Asrc = A  + (size_t)(r0 + wid * 32 + srow) * Ec + scol;
    const u16* Bsrc = Bt + (size_t)(n0 + wid * 32 + srow) * Ec + scol;

#define STAGE256(tile, buf)                                                     \
    do {                                                                        \
        const int _k0 = (tile) * 64;                                            \
        _Pragma("unroll")                                                       \
        for (int i = 0; i < 4; ++i) {                                           \
            gload16(Asrc + (size_t)(i * 8) * Ec + _k0,                          \
                    &lds[buf][0][(wid * 32 + i * 8) * 64]);                     \
            gload16(Bsrc + (size_t)(i * 8) * Ec + _k0,                          \
                    &lds[buf][1][(wid * 32 + i * 8) * 64]);                     \
        }                                                                       \
    } while (0)

    STAGE256(0, 0);
    for (int tt = 0; tt < 16; ++tt) {
        const int buf = tt & 1;
        if (tt + 1 < 16) {
            STAGE256(tt + 1, buf ^ 1);
            asm volatile("s_waitcnt vmcnt(8)" ::: "memory"); // my tile-tt loads
        } else {
            asm volatile("s_waitcnt vmcnt(0)" ::: "memory");
        }
        __builtin_amdgcn_s_barrier();   // ALL waves' tile-tt DMAs landed

        u16x8 breg[4][2];
#pragma unroll
        for (int cf = 0; cf < 4; ++cf)
#pragma unroll
            for (int ks = 0; ks < 2; ++ks) {
                const int row = wn * 64 + cf * 16 + rl;
                breg[cf][ks] = *(const u16x8*)
                    &lds[buf][1][row * 64 + ((ks * 32 + hi * 8) ^ ((rl & 7) << 3))];
            }
#pragma unroll
        for (int q = 0; q < 4; ++q) {
            u16x8 areg[2][2];
#pragma unroll
            for (int rfi = 0; rfi < 2; ++rfi)
#pragma unroll
                for (int ks = 0; ks < 2; ++ks) {
                    const int row = wm * 128 + (q * 2 + rfi) * 16 + rl;
                    areg[rfi][ks] = *(const u16x8*)
                        &lds[buf][0][row * 64 + ((ks * 32 + hi * 8) ^ ((rl & 7) << 3))];
                }
            __builtin_amdgcn_s_setprio(1);
#pragma unroll
            for (int rfi = 0; rfi < 2; ++rfi)
#pragma unroll
                for (int cf = 0; cf < 4; ++cf)
#pragma unroll
                    for (int ks = 0; ks < 2; ++ks)
                        acc[q * 2 + rfi][cf] =
                            mfma16(breg[cf][ks], areg[rfi][ks], acc[q * 2 + rfi][cf]);
            __builtin_amdgcn_s_setprio(0);
        }
        __builtin_amdgcn_s_barrier();   // reads of buf done before overwrite
    }
#undef STAGE256

    u16* Cout = wsel == 0 ? Qo : wsel == 1 ? Ko : wsel == 2 ? Vo : Go;
    const float2* tab = wsel == 0 ? tabQ : tabK;

#pragma unroll
    for (int rf = 0; rf < 8; ++rf) {
        const int row = r0 + wm * 128 + rf * 16 + rl;
#pragma unroll
        for (int cf = 0; cf < 4; ++cf) {
            const int col0 = n0 + wn * 64 + cf * 16 + hi * 4;
            f32x4 v = acc[rf][cf];
            if (wsel <= 1) { // xPos rotate: pairs (0,1),(2,3) lane-local
                const size_t tb = (size_t)(row & 2047) * 64 + ((col0 >> 1) & 63);
                const float2 c0 = tab[tb];
                const float2 c1 = tab[tb + 1];
                float e0 = v[0], o0 = v[1], e1 = v[2], o1 = v[3];
                v[0] = e0 * c0.x - o0 * c0.y;
                v[1] = o0 * c0.x + e0 * c0.y;
                v[2] = e1 * c1.x - o1 * c1.y;
                v[3] = o1 * c1.x + e1 * c1.y;
            } else if (wsel == 3) { // silu
#pragma unroll
                for (int r = 0; r < 4; ++r) v[r] = v[r] / (1.f + expf(-v[r]));
            }
            u16x4 pk;
#pragma unroll
            for (int r = 0; r < 4; ++r) pk[r] = f2bf(v[r]);
            *(u16x4*)(Cout + (size_t)row * Ec + col0) = pk;
        }
    }
}

// ---------------------------------------------------------------------------
// Final GEMM: out(f32) = Z x WoT^T.  128x64 tile, BK=32, 4 waves, grid
// (32,16)=512 blocks -> 2 blocks/CU.  3 gloads/wave/tile, vmcnt(3),
// 8 MFMA/tile, BK=32 swizzle (AIDX).
// ---------------------------------------------------------------------------
__global__ __launch_bounds__(256) void mgemmO(const u16* __restrict__ A,
                                              const u16* __restrict__ Bt,
                                              float* __restrict__ Cout)
{
    const int t = threadIdx.x, lane = t & 63, w = t >> 6;
    const int rl = lane & 15, hi = lane >> 4;
    const int r0 = blockIdx.x * 128;
    const int n0 = blockIdx.y * 64;

    __shared__ u16 Ab[2][128 * 32]; // 16 KiB
    __shared__ u16 Bb[2][64 * 32];  //  8 KiB

    f32x4 acc[2][4] = {};

    const int srow = lane >> 2;
    const int schunk = (lane & 3) ^ ((lane >> 3) & 3);
    const u16* Asrc = A  + (size_t)(r0 + w * 32 + srow) * Ec + schunk * 8;
    const u16* Bsrc = Bt + (size_t)(n0 + w * 16 + srow) * Ec + schunk * 8;

#define STAGEO(tile_, buf_)                                                   \
    do {                                                                      \
        const int _k0 = (tile_) * 32;                                         \
        gload16(Asrc + _k0,                   &Ab[buf_][(w * 32) * 32]);      \
        gload16(Asrc + (size_t)16 * Ec + _k0, &Ab[buf_][(w * 32 + 16) * 32]); \
        gload16(Bsrc + _k0,                   &Bb[buf_][(w * 16) * 32]);      \
    } while (0)

    STAGEO(0, 0);
    for (int tt = 0; tt < 32; ++tt) {
        const int buf = tt & 1;
        if (tt + 1 < 32) {
            STAGEO(tt + 1, buf ^ 1);
            asm volatile("s_waitcnt vmcnt(3)" ::: "memory");
        } else {
            asm volatile("s_waitcnt vmcnt(0)" ::: "memory");
        }
        __builtin_amdgcn_s_barrier();

        u16x8 breg[4], areg[2];
#pragma unroll
        for (int cf = 0; cf < 4; ++cf)
            breg[cf] = *(const u16x8*)&Bb[buf][AIDX(cf * 16 + rl, hi)];
#pragma unroll
        for (int rfi = 0; rfi < 2; ++rfi)
            areg[rfi] = *(const u16x8*)&Ab[buf][AIDX(w * 32 + rfi * 16 + rl, hi)];
        __builtin_amdgcn_s_setprio(1);
#pragma unroll
        for (int rfi = 0; rfi < 2; ++rfi)
#pragma unroll
            for (int cf = 0; cf < 4; ++cf)
                acc[rfi][cf] = mfma16(breg[cf], areg[rfi], acc[rfi][cf]);
        __builtin_amdgcn_s_setprio(0);
        __builtin_amdgcn_s_barrier();
    }
#undef STAGEO

#pragma unroll
    for (int rfi = 0; rfi < 2; ++rfi) {
        const int row = r0 + w * 32 + rfi * 16 + rl;
#pragma unroll
        for (int cf = 0; cf < 4; ++cf) {
            const int col0 = n0 + cf * 16 + hi * 4;
            *(f32x4*)(Cout + (size_t)row * Ec + col0) = acc[rfi][cf];
        }
    }
}

// ---------------------------------------------------------------------------
// Retention + fused GroupNorm*gate (r13 proven form: QBLK=64, 4 waves,
// double-buffered K/V, 2 barriers/chunk, grid 512).
// id = a*16 + slot: slot&7 = xcd hosts heads {h, 7-h} (L2-resident K/V,
// balanced pair sums); a = id>>4, rb = a<16 ? 31-a : a-16 (CU co-hosts
// rb=31-a and rb=a -> constant chunk sum + m114 cross-block overlap).
// r14 (single-buffer, 3 blk/CU) and r15 (QBLK=128, grid 256) both measured
// neutral-to-worse: critical path is per-chunk barrier-serialized latency,
// and this config minimizes it.
// ---------------------------------------------------------------------------
__global__ __launch_bounds__(256) void ret_gn(const u16* __restrict__ Q,
                                              const u16* __restrict__ K,
                                              const u16* __restrict__ V,
                                              const u16* __restrict__ G,
                                              const float* __restrict__ gw,
                                              const float* __restrict__ gbias,
                                              u16* __restrict__ Z)
{
    const int t = threadIdx.x, lane = t & 63, w = t >> 6;
    const int rl = lane & 15, hi = lane >> 4;
    const int id = blockIdx.x;
    const int slot = id & 15;
    const int a  = id >> 4;
    const int rb = (a < 16) ? (31 - a) : (a - 16);
    const int b = slot >> 3;
    const int h = b == 0 ? (slot & 7) : 7 - (slot & 7);

    __shared__ u16 Ks[2][64][136];
    __shared__ u16 Vt[2][128][68]; // V transposed: Vt[buf][d][m]
    __shared__ u16 Ss[64][72];     // S[n][m]

    const float lga = -3.4657359027997265f; // log(1/32)
    const float lgb = -6.2383246250395075f; // log(1/512)
    const float gamma = 1.f - expf(lga + (float)h * (lgb - lga) * (1.f / 7.f));
    const float lg2 = log2f(gamma);

    int c_lo = 0;
    {
        float cut = 9.2103404f / (-logf(gamma)); // weight >= ~1e-4
        int mmin = rb * 64 - (int)cut;
        if (mmin > 0) c_lo = mmin >> 6;
    }

    // per-lane staging geometry
    const int ki = t >> 2,        kq = (t & 3) * 32;  // K: row, 32-elem quarter
    const int vm4 = (t & 15) * 4, vd = (t >> 4) * 8;  // V: 4 rows, 8-d segment
    const u16* Kg0 = K + (size_t)(b * Sc) * Ec + h * Dc;
    const u16* Vg0 = V + (size_t)(b * Sc) * Ec + h * Dc;

    // ---- issue first K/V chunk loads (independent of LDS) ----
    u16x8 kreg[4], vreg[4];
    {
        const u16* Kg = Kg0 + (size_t)(c_lo * 64 + ki) * Ec + kq;
#pragma unroll
        for (int r = 0; r < 4; ++r) kreg[r] = *(const u16x8*)(Kg + r * 8);
        const u16* Vg = Vg0 + (size_t)(c_lo * 64 + vm4) * Ec + vd;
#pragma unroll
        for (int r = 0; r < 4; ++r) vreg[r] = *(const u16x8*)(Vg + (size_t)r * Ec);
    }

    // ---- stage Q through Ks[0]; every wave pulls ALL 64 rows to registers ----
    {
        const int i = t >> 2, q = (t & 3) * 32;
        const u16* Qg = Q + (size_t)(b * Sc + rb * 64 + i) * Ec + h * Dc + q;
        u16x8 v0 = *(const u16x8*)(Qg);
        u16x8 v1 = *(const u16x8*)(Qg + 8);
        u16x8 v2 = *(const u16x8*)(Qg + 16);
        u16x8 v3 = *(const u16x8*)(Qg + 24);
        *(u16x8*)&Ks[0][i][q]      = v0;
        *(u16x8*)&Ks[0][i][q + 8]  = v1;
        *(u16x8*)&Ks[0][i][q + 16] = v2;
        *(u16x8*)&Ks[0][i][q + 24] = v3;
    }
    __syncthreads();
    u16x8 qf[4][4];
#pragma unroll
    for (int nt = 0; nt < 4; ++nt)
#pragma unroll
        for (int ks = 0; ks < 4; ++ks)
            qf[nt][ks] = *(const u16x8*)&Ks[0][nt * 16 + rl][ks * 32 + hi * 8];
    __syncthreads(); // Q frags read before chunk loop overwrites Ks[0]

    // decay: wgt(n,m) = nf[nt] * mf[reg]
    float mf[4];
#pragma unroll
    for (int reg = 0; reg < 4; ++reg)
        mf[reg] = exp2f(-lg2 * (float)(w * 16 + hi * 4 + reg));
    float nf[4];
#pragma unroll
    for (int nt = 0; nt < 4; ++nt)
        nf[nt] = exp2f(lg2 * (float)((rb - c_lo) * 64 + nt * 16 + rl));
    const float ginv64 = exp2f(-lg2 * 64.f);

    f32x4 yacc[8] = {};

    for (int c = c_lo; c <= rb; ++c) {
        const int cur = c & 1;
        // regs -> LDS (double-buffered: no barrier needed before write)
#pragma unroll
        for (int r = 0; r < 4; ++r)
            *(u16x8*)&Ks[cur][ki][kq + r * 8] = kreg[r];
#pragma unroll
        for (int j = 0; j < 8; ++j) {
            u16x4 p;
            p[0] = vreg[0][j]; p[1] = vreg[1][j]; p[2] = vreg[2][j]; p[3] = vreg[3][j];
            *(u16x4*)&Vt[cur][vd + j][vm4] = p;
        }
        __syncthreads();
        if (c < rb) { // prefetch next chunk into REGISTERS under compute
            const u16* Kg = Kg0 + (size_t)((c + 1) * 64 + ki) * Ec + kq;
#pragma unroll
            for (int r = 0; r < 4; ++r) kreg[r] = *(const u16x8*)(Kg + r * 8);
            const u16* Vg = Vg0 + (size_t)((c + 1) * 64 + vm4) * Ec + vd;
#pragma unroll
            for (int r = 0; r < 4; ++r) vreg[r] = *(const u16x8*)(Vg + (size_t)r * Ec);
        }

        // QK^T: wave owns m-strip [w*16, w*16+16); S^T frag -> Ss[n][m]
        __builtin_amdgcn_s_setprio(1);
        u16x8 kf[4];
#pragma unroll
        for (int ks = 0; ks < 4; ++ks)
            kf[ks] = *(const u16x8*)&Ks[cur][w * 16 + rl][ks * 32 + hi * 8];
#pragma unroll
        for (int nt = 0; nt < 4; ++nt) {
            f32x4 s = {};
#pragma unroll
            for (int ks = 0; ks < 4; ++ks)
                s = mfma16(kf[ks], qf[nt][ks], s);
            // lane holds S[n = nt*16+rl][m = w*16+hi*4+reg], reg=0..3
            u16x4 pk;
#pragma unroll
            for (int reg = 0; reg < 4; ++reg) {
                float wgt = nf[nt] * mf[reg];
                if (c == rb && (w * 16 + hi * 4 + reg) > (nt * 16 + rl)) wgt = 0.f;
                pk[reg] = f2bf(s[reg] * wgt);
            }
            *(u16x4*)&Ss[nt * 16 + rl][w * 16 + hi * 4] = pk;
        }
        __builtin_amdgcn_s_setprio(0);
        __syncthreads();

        // Y += S V (swapped): lane holds Y[n=w*16+rl][d=ct*16+hi*4+reg]
        u16x8 sf0 = *(const u16x8*)&Ss[w * 16 + rl][hi * 8];
        u16x8 sf1 = *(const u16x8*)&Ss[w * 16 + rl][32 + hi * 8];
        __builtin_amdgcn_s_setprio(1);
#pragma unroll
        for (int ct = 0; ct < 8; ++ct) {
            u16x8 vf0 = *(const u16x8*)&Vt[cur][ct * 16 + rl][hi * 8];
            u16x8 vf1 = *(const u16x8*)&Vt[cur][ct * 16 + rl][32 + hi * 8];
            yacc[ct] = mfma16(vf0, sf0, yacc[ct]);
            yacc[ct] = mfma16(vf1, sf1, yacc[ct]);
        }
        __builtin_amdgcn_s_setprio(0);
#pragma unroll
        for (int nt = 0; nt < 4; ++nt) nf[nt] *= ginv64;
    }

    // ---- fused GroupNorm * gate epilogue (one row per thread) ----
    const int nloc = w * 16 + rl;
    const size_t row = (size_t)(b * Sc + rb * 64 + nloc);
    float s = 0.f, sq = 0.f;
#pragma unroll
    for (int ct = 0; ct < 8; ++ct)
#pragma unroll
        for (int reg = 0; reg < 4; ++reg) {
            float v = yacc[ct][reg];
            s += v; sq += v * v;
        }
    s  += __shfl_xor(s, 16);  sq += __shfl_xor(sq, 16);
    s  += __shfl_xor(s, 32);  sq += __shfl_xor(sq, 32);
    const float mu  = s * (1.f / 128.f);
    const float var = sq * (1.f / 128.f) - mu * mu;
    const float inv = rsqrtf(var + 1e-5f);
#pragma unroll
    for (int ct = 0; ct < 8; ++ct) {
        const int col0 = h * Dc + ct * 16 + hi * 4;
        const f32x4 w4 = *(const f32x4*)(gw + col0);
        const f32x4 b4 = *(const f32x4*)(gbias + col0);
        const u16x4 g4 = *(const u16x4*)(G + row * Ec + col0);
        u16x4 z4;
#pragma unroll
        for (int reg = 0; reg < 4; ++reg)
            z4[reg] = f2bf(((yacc[ct][reg] - mu) * inv * w4[reg] + b4[reg]) * bf2f(g4[reg]));
        *(u16x4*)(Z + row * Ec + col0) = z4;
    }
}

} // anonymous namespace

extern "C" void kernel_launch(void* const* d_in, const int* in_sizes, int n_in,
                              void* d_out, int out_size, void* d_ws, size_t ws_size,
                              hipStream_t stream)
{
    const float* X    = (const float*)d_in[0];
    const float* W_Q  = (const float*)d_in[1];
    const float* W_K  = (const float*)d_in[2];
    const float* W_V  = (const float*)d_in[3];
    const float* W_G  = (const float*)d_in[4];
    const float* W_O  = (const float*)d_in[5];
    const float* gw   = (const float*)d_in[6];
    const float* gb   = (const float*)d_in[7];

    char* ws = (char*)d_ws;
    const size_t NX = (size_t)Mc * Ec;          // 4 Mi elements
    u16*    Xb   = (u16*)ws;                ws += NX * 2;              // 8 MB
    u16*    WqT  = (u16*)ws;                ws += (size_t)Ec * Ec * 2; // 2 MB (x4, contiguous)
    u16*    WkT  = (u16*)ws;                ws += (size_t)Ec * Ec * 2;
    u16*    WvT  = (u16*)ws;                ws += (size_t)Ec * Ec * 2;
    u16*    WgT  = (u16*)ws;                ws += (size_t)Ec * Ec * 2;
    u16*    WoT  = (u16*)ws;                ws += (size_t)Ec * Ec * 2;
    float2* tabQ = (float2*)ws;             ws += (size_t)Sc * 64 * sizeof(float2); // 1 MB
    float2* tabK = (float2*)ws;             ws += (size_t)Sc * 64 * sizeof(float2);
    u16*    Qb   = (u16*)ws;                ws += NX * 2;              // 8 MB
    u16*    Kb   = (u16*)ws;                ws += NX * 2;
    u16*    Vb   = (u16*)ws;                ws += NX * 2;
    u16*    Gb   = (u16*)ws;                ws += NX * 2;
    u16*    Zb   = (u16*)ws;                ws += NX * 2;
    (void)WkT; (void)WvT;

    prep<<<dim3(7680), dim3(256), 0, stream>>>(X, W_Q, W_K, W_V, W_G, W_O,
                                               Xb, WqT, WgT, tabQ, tabK);

    mgemm4<<<dim3(Mc / 256, 16), dim3(512), 0, stream>>>(Xb, WqT, Qb, Kb, Vb, Gb, tabQ, tabK);

    ret_gn<<<dim3(512), dim3(256), 0, stream>>>(Qb, Kb, Vb, Gb, gw, gb, Zb);

    mgemmO<<<dim3(Mc / 128, Ec / 64), dim3(256), 0, stream>>>(Zb, WoT, (float*)d_out);
}